// Round 9
// baseline (209.685 us; speedup 1.0000x reference)
//
#include <hip/hip_runtime.h>
#include <hip/hip_bf16.h>
#include <cmath>

// Problem constants
#define Bc   32
#define Sc_  512
#define Hc   768
#define NHc  12
#define DHc  64
#define Mc   (Bc * Sc_)     // 16384 tokens
#define Ntot (3 * Hc)       // 2304 fused output cols (Q|K|V)

// 0.125 (1/sqrt(DH)) * log2(e): folded into Q so softmax is exp2(s)
#define QSCALE 0.18033688011112042f

typedef __attribute__((ext_vector_type(8))) short short8v;   // 8 bf16 (4 VGPRs)
typedef __attribute__((ext_vector_type(8))) unsigned short ushort8v;
typedef __attribute__((ext_vector_type(4))) float f32x4;     // MFMA acc

static __device__ __forceinline__ ushort f2b(float f) {
    __hip_bfloat16 h = __float2bfloat16(f);
    return *reinterpret_cast<ushort*>(&h);
}
static __device__ __forceinline__ ushort2 f2b2(float a, float b) {
    __hip_bfloat162 h = __float22bfloat162_rn(float2{a, b});
    return *reinterpret_cast<ushort2*>(&h);
}

// async global->LDS, 16B per lane. HW writes lane i to (wave-uniform lds)+i*16B.
static __device__ __forceinline__ void gl2lds(const ushort* g, ushort* l) {
    __builtin_amdgcn_global_load_lds(
        (const __attribute__((address_space(1))) unsigned int*)g,
        (__attribute__((address_space(3))) unsigned int*)l, 16, 0, 0);
}

// tanh(x) = 1 - 2/(exp2(2x*log2e)+1); exact at +/-inf via rcp(inf)=0
static __device__ __forceinline__ float fast_tanh(float x) {
    float e = __builtin_amdgcn_exp2f(x * 2.885390081777927f);
    return 1.0f - 2.0f * __builtin_amdgcn_rcpf(e + 1.0f);
}

// ---------------------------------------------------------------------------
// Kernel 0 (R0 exact): fp32 -> bf16 tiled repack, coalesced both sides.
//   Xt [m/128][k/8][m%128][8], Wt [n/128][k/8][n%128][8].
// ---------------------------------------------------------------------------
__global__ __launch_bounds__(256) void convert_pack(
    const float* __restrict__ X,
    const float* __restrict__ Wq, const float* __restrict__ Wk,
    const float* __restrict__ Wv,
    const float* __restrict__ bq, const float* __restrict__ bk,
    const float* __restrict__ bv,
    ushort* __restrict__ Xt, ushort* __restrict__ Wt, float* __restrict__ bbp)
{
    const int bx = blockIdx.x;
    const int panel = bx / 12, kcg = bx % 12;   // kcg = 64-k group
    const int t = threadIdx.x;

    __shared__ ushort T[128][68];

    const float* base;
    ushort* out;
    if (panel < 128) {
        base = X + (size_t)panel * 128 * Hc;
        out  = Xt + (size_t)panel * (96 * 1024);
    } else {
        int nblk = panel - 128;                 // 0..17
        int n0 = nblk * 128;
        int z = n0 / Hc;
        int nn0 = n0 - z * Hc;
        const float* W = (z == 0) ? Wq : (z == 1) ? Wk : Wv;
        base = W + (size_t)nn0 * Hc;
        out  = Wt + (size_t)nblk * (96 * 1024);
    }
    const int k0 = kcg * 64;

    const int slot = t & 15, rsub = t >> 4;
    #pragma unroll
    for (int rnd = 0; rnd < 8; ++rnd) {
        int row = rnd * 16 + rsub;
        const float* p = base + (size_t)row * Hc + k0 + slot * 4;
        float4 f = *(const float4*)p;
        ushort2 h0 = f2b2(f.x, f.y);
        ushort2 h1 = f2b2(f.z, f.w);
        ushort4 u;
        u.x = h0.x; u.y = h0.y; u.z = h1.x; u.w = h1.y;
        *(ushort4*)&T[row][slot * 4] = u;
    }
    __syncthreads();

    const int row_w = t & 127, kh = t >> 7;
    #pragma unroll
    for (int rnd = 0; rnd < 4; ++rnd) {
        int kc_l = rnd * 2 + kh;
        ushort4 lo = *(const ushort4*)&T[row_w][kc_l * 8];
        ushort4 hi = *(const ushort4*)&T[row_w][kc_l * 8 + 4];
        ushort8v o;
        o[0] = lo.x; o[1] = lo.y; o[2] = lo.z; o[3] = lo.w;
        o[4] = hi.x; o[5] = hi.y; o[6] = hi.z; o[7] = hi.w;
        *(ushort8v*)&out[(size_t)(kcg * 8 + kc_l) * 1024 + row_w * 8] = o;
    }

    if (bx == 0) {
        for (int i = t; i < Ntot; i += 256) {
            int z2 = i / Hc, nn = i - z2 * Hc;
            bbp[i] = ((z2 == 0) ? bq : (z2 == 1) ? bk : bv)[nn];
        }
    }
}

// ---------------------------------------------------------------------------
// Kernel 1: fused QKV projection, 128x128 tile, BK=32, low-VGPR (R7 K-loop,
// unchanged). NEW: LDS-staged epilogue — after the K-loop the 16 KB staging
// buffer S is dead; the C tile is staged bf16 in two 64-row rounds and
// written out as 16B dwordx4 stores along each layout's contiguous axis
// (8 wide stores/thread vs 64 scalar 2B stores). Values bit-identical.
// Epilogue layouts (per head, head stride S*DH = 32768):
//   Qb: [s][d] row-major, pre-scaled by QSCALE
//   Kt: [kb=s/64][dchunk=d/8][s%64][8]
//   Vt: [kb=s/64][keychunk=(s%64)/8][d][8]
// ---------------------------------------------------------------------------
__global__ __launch_bounds__(256, 4) void qkv_mfma(
    const ushort* __restrict__ Xt, const ushort* __restrict__ Wt,
    const float* __restrict__ bbp,
    ushort* __restrict__ Qb, ushort* __restrict__ Kt, ushort* __restrict__ Vt)
{
    const int tid = threadIdx.x;
    const int wave = tid >> 6, lane = tid & 63;
    const int quad = lane >> 4, l16 = lane & 15;
    const int wr = wave >> 1, wc = wave & 1;
    const int m0 = blockIdx.x * 128;
    const int n0 = blockIdx.y * 128;

    __shared__ __align__(16) ushort S[8192];    // A-half | B-half; C-stage after

    f32x4 acc[4][4];
    #pragma unroll
    for (int i = 0; i < 4; ++i)
        #pragma unroll
        for (int j = 0; j < 4; ++j) acc[i][j] = (f32x4)(0.f);

    const ushort* gA = Xt + (size_t)blockIdx.x * (96 * 1024) + wave * 1024 + lane * 8;
    const ushort* gB = Wt + (size_t)blockIdx.y * (96 * 1024) + wave * 1024 + lane * 8;
    ushort* lA = S + wave * 1024;
    ushort* lB = S + 4096 + wave * 1024;

    for (int t = 0; t < 24; ++t) {
        const ushort* ga = gA + t * 4096;
        const ushort* gb = gB + t * 4096;
        gl2lds(ga,       lA);
        gl2lds(ga + 512, lA + 512);
        gl2lds(gb,       lB);
        gl2lds(gb + 512, lB + 512);
        __syncthreads();

        short8v a[4];
        #pragma unroll
        for (int i = 0; i < 4; ++i)
            a[i] = *(const short8v*)&S[quad * 1024 + (wr * 64 + i * 16 + l16) * 8];
        #pragma unroll
        for (int j = 0; j < 4; ++j) {
            short8v b = *(const short8v*)
                &S[4096 + quad * 1024 + (wc * 64 + j * 16 + l16) * 8];
            #pragma unroll
            for (int i = 0; i < 4; ++i)
                acc[i][j] = __builtin_amdgcn_mfma_f32_16x16x32_bf16(
                    a[i], b, acc[i][j], 0, 0, 0);
        }
        __syncthreads();
    }

    // ---- LDS-staged epilogue: two 64-row rounds through S (16 KB) ----
    // C layout per 16x16 tile: col=l16 (n), row=quad*4+r (m).
    // Round hh covers tiles i in {2hh, 2hh+1}; staged row sm = wr*32 +
    // i2*16 + quad*4 + r  <->  m_loc = (sm>>5)*64 + hh*32 + (sm&31).
    const int z = n0 / Hc;
    #pragma unroll
    for (int hh = 0; hh < 2; ++hh) {
        if (z == 2) {
            // transposed stage [n][sm]: ushort4 writes (4 consecutive m)
            #pragma unroll
            for (int j = 0; j < 4; ++j) {
                const int n = wc * 64 + j * 16 + l16;
                const float bias = bbp[n0 + n];
                #pragma unroll
                for (int i2 = 0; i2 < 2; ++i2) {
                    const int i = hh * 2 + i2;
                    const int smb = wr * 32 + i2 * 16 + quad * 4;
                    ushort4 o4;
                    o4.x = f2b(acc[i][j][0] + bias);
                    o4.y = f2b(acc[i][j][1] + bias);
                    o4.z = f2b(acc[i][j][2] + bias);
                    o4.w = f2b(acc[i][j][3] + bias);
                    *(ushort4*)&S[n * 64 + smb] = o4;
                }
            }
        } else {
            // row stage [sm][n]: b16 writes
            #pragma unroll
            for (int j = 0; j < 4; ++j) {
                const int n = wc * 64 + j * 16 + l16;
                const float bias = bbp[n0 + n];
                #pragma unroll
                for (int i2 = 0; i2 < 2; ++i2) {
                    const int i = hh * 2 + i2;
                    const int smb = wr * 32 + i2 * 16 + quad * 4;
                    #pragma unroll
                    for (int r = 0; r < 4; ++r) {
                        float v = acc[i][j][r] + bias;
                        if (z == 0) v *= QSCALE;
                        S[(smb + r) * 128 + n] = f2b(v);
                    }
                }
            }
        }
        __syncthreads();

        // copy out: 4 x 16B per thread along each layout's contiguous axis
        if (z == 2) {
            #pragma unroll
            for (int cc = 0; cc < 4; ++cc) {
                const int n   = wave * 32 + cc * 8 + (lane & 7);
                const int smv = (lane >> 3) * 8;
                const int m_loc = (smv >> 5) * 64 + hh * 32 + (smv & 31);
                const int m_g = m0 + m_loc;
                const int bb2 = m_g >> 9, s0 = m_g & 511;   // s0&7 == 0
                const int nn = n0 + n - 1536;
                const int hd = nn >> 6, d = nn & 63;
                const size_t hb = (size_t)(bb2 * NHc + hd) * (Sc_ * DHc);
                const size_t ga = hb + (s0 >> 6) * 4096 + ((s0 & 63) >> 3) * 512
                                + (size_t)d * 8;
                *(ushort8v*)&Vt[ga] = *(const ushort8v*)&S[n * 64 + smv];
            }
        } else {
            #pragma unroll
            for (int cc = 0; cc < 4; ++cc) {
                const int chunk = wave * 256 + cc * 64 + lane;
                const int sm = chunk >> 4, nc = chunk & 15;
                const int m_loc = (sm >> 5) * 64 + hh * 32 + (sm & 31);
                const int m_g = m0 + m_loc;
                const int bb2 = m_g >> 9, s0 = m_g & 511;
                const int nn = n0 + nc * 8 - z * Hc;
                const int hd = nn >> 6, d0 = nn & 63;      // 8-aligned
                const size_t hb = (size_t)(bb2 * NHc + hd) * (Sc_ * DHc);
                const ushort8v val = *(const ushort8v*)&S[sm * 128 + nc * 8];
                if (z == 0) {
                    *(ushort8v*)&Qb[hb + (size_t)s0 * 64 + d0] = val;
                } else {
                    *(ushort8v*)&Kt[hb + (s0 >> 6) * 4096 + (d0 >> 3) * 512
                                    + (s0 & 63) * 8] = val;
                }
            }
        }
        if (hh == 0) __syncthreads();
    }
}

// ---------------------------------------------------------------------------
// Kernel 2 (R8, kept): attention, 128 q per block (wave = 32 q = 2 u-tiles),
// 1536 blocks, K/V register time-share, 4 waves/SIMD.
// ---------------------------------------------------------------------------
__global__ __launch_bounds__(256, 4) void attn_mfma(
    const ushort* __restrict__ Qb, const ushort* __restrict__ Kt,
    const ushort* __restrict__ Vt, float* __restrict__ out)
{
    const int bid = blockIdx.x;
    const int super = bid >> 5, l = bid & 31;
    const int head_lin = super * 8 + (l & 7);     // 0..383
    const int qq = l >> 3;                        // q-quarter 0..3
    const int b = head_lin / NHc, h = head_lin % NHc;

    const int wave = threadIdx.x >> 6;
    const int lane = threadIdx.x & 63;
    const int quad = lane >> 4, l16 = lane & 15;
    const int q0 = qq * 128 + wave * 32;          // wave owns q0..q0+31
    const int sw = l16 & 7;                       // XOR swizzle key

    const size_t head = (size_t)head_lin * (Sc_ * DHc);
    const ushort* __restrict__ Q = Qb + head;
    const ushort* __restrict__ K = Kt + head;
    const ushort* __restrict__ V = Vt + head;

    __shared__ __align__(16) ushort Plds[4][2048];   // wave-private, 2 u-tiles

    short8v aq[2][2];
    #pragma unroll
    for (int u = 0; u < 2; ++u)
        #pragma unroll
        for (int hf = 0; hf < 2; ++hf)
            aq[u][hf] = *(const short8v*)
                &Q[(size_t)(q0 + u * 16 + l16) * DHc + hf * 32 + quad * 8];

    short8v ones;
    #pragma unroll
    for (int i = 0; i < 8; ++i) ones[i] = (short)0x3F80;   // bf16 1.0

    f32x4 o[2][4], rsum[2];
    #pragma unroll
    for (int u = 0; u < 2; ++u) {
        rsum[u] = (f32x4)(0.f);
        #pragma unroll
        for (int t = 0; t < 4; ++t) o[u][t] = (f32x4)(0.f);
    }

    for (int kb = 0; kb < 8; ++kb) {
        const ushort* Kb_ = K + kb * 4096;
        const ushort* Vb_ = V + kb * 4096;

        // ---- QK phase: only kf live ----
        {
            short8v kf[4][2];
            #pragma unroll
            for (int t = 0; t < 4; ++t) {
                kf[t][0] = *(const short8v*)&Kb_[quad * 512 + (t * 16 + l16) * 8];
                kf[t][1] = *(const short8v*)&Kb_[(4 + quad) * 512 + (t * 16 + l16) * 8];
            }

            #pragma unroll
            for (int u = 0; u < 2; ++u) {
                // S^T: D[key=quad*4+r][q=l16]
                f32x4 sa[4];
                #pragma unroll
                for (int t = 0; t < 4; ++t) {
                    f32x4 s = __builtin_amdgcn_mfma_f32_16x16x32_bf16(
                        kf[t][0], aq[u][0], (f32x4)(0.f), 0, 0, 0);
                    sa[t] = __builtin_amdgcn_mfma_f32_16x16x32_bf16(
                        kf[t][1], aq[u][1], s, 0, 0, 0);
                }

                // p = exp2(s~), pack to bf16, stage to LDS (wave-private)
                #pragma unroll
                for (int t = 0; t < 4; ++t) {
                    float p0 = __builtin_amdgcn_exp2f(sa[t][0]);
                    float p1 = __builtin_amdgcn_exp2f(sa[t][1]);
                    float p2 = __builtin_amdgcn_exp2f(sa[t][2]);
                    float p3 = __builtin_amdgcn_exp2f(sa[t][3]);
                    ushort2 lo = f2b2(p0, p1);
                    ushort2 hi = f2b2(p2, p3);
                    ushort4 pk;
                    pk.x = lo.x; pk.y = lo.y; pk.z = hi.x; pk.w = hi.y;
                    int c = t * 2 + (quad >> 1);            // key chunk 0..7
                    int addr = u * 1024 + l16 * 64 + ((c ^ sw) * 8) + (quad & 1) * 4;
                    *(ushort4*)&Plds[wave][addr] = pk;
                }
            }
        }

        // ---- PV phase: only vf live (re-uses kf's registers) ----
        {
            short8v vf[4][2];
            #pragma unroll
            for (int t = 0; t < 4; ++t) {
                vf[t][0] = *(const short8v*)&Vb_[quad * 512 + (t * 16 + l16) * 8];
                vf[t][1] = *(const short8v*)&Vb_[(4 + quad) * 512 + (t * 16 + l16) * 8];
            }

            #pragma unroll
            for (int u = 0; u < 2; ++u) {
                // P A-frags (q = l16, key chunk = hf*4+quad, swizzled)
                short8v pa0 = *(const short8v*)
                    &Plds[wave][u * 1024 + l16 * 64 + ((quad ^ sw) * 8)];
                short8v pa1 = *(const short8v*)
                    &Plds[wave][u * 1024 + l16 * 64 + (((4 + quad) ^ sw) * 8)];

                // row sums via ones-MFMA
                rsum[u] = __builtin_amdgcn_mfma_f32_16x16x32_bf16(
                    pa0, ones, rsum[u], 0, 0, 0);
                rsum[u] = __builtin_amdgcn_mfma_f32_16x16x32_bf16(
                    pa1, ones, rsum[u], 0, 0, 0);

                // PV: O[q=quad*4+r][d=l16]
                #pragma unroll
                for (int t2 = 0; t2 < 4; ++t2) {
                    o[u][t2] = __builtin_amdgcn_mfma_f32_16x16x32_bf16(
                        pa0, vf[t2][0], o[u][t2], 0, 0, 0);
                    o[u][t2] = __builtin_amdgcn_mfma_f32_16x16x32_bf16(
                        pa1, vf[t2][1], o[u][t2], 0, 0, 0);
                }
            }
        }
    }

    // Epilogue: normalize, tanh, store.
    #pragma unroll
    for (int u = 0; u < 2; ++u) {
        #pragma unroll
        for (int r = 0; r < 4; ++r) {
            float inv = __builtin_amdgcn_rcpf(rsum[u][r]);
            int q = q0 + u * 16 + quad * 4 + r;
            size_t base = ((size_t)b * Sc_ + q) * Hc + h * DHc;
            #pragma unroll
            for (int t2 = 0; t2 < 4; ++t2)
                out[base + t2 * 16 + l16] = fast_tanh(o[u][t2][r] * inv);
        }
    }
}

extern "C" void kernel_launch(void* const* d_in, const int* in_sizes, int n_in,
                              void* d_out, int out_size, void* d_ws, size_t ws_size,
                              hipStream_t stream) {
    const float* X  = (const float*)d_in[0];
    const float* Wq = (const float*)d_in[1];
    const float* bq = (const float*)d_in[2];
    const float* Wk = (const float*)d_in[3];
    const float* bk = (const float*)d_in[4];
    const float* Wv = (const float*)d_in[5];
    const float* bv = (const float*)d_in[6];
    float* out = (float*)d_out;

    ushort* Qb  = (ushort*)d_ws;
    ushort* Kt  = Qb + (size_t)Mc * Hc;
    ushort* Vt  = Kt + (size_t)Mc * Hc;
    ushort* Xt  = Vt + (size_t)Mc * Hc;
    ushort* Wt  = Xt + (size_t)Mc * Hc;
    float*  bbp = (float*)(Wt + (size_t)Ntot * Hc);

    convert_pack<<<dim3(1752), 256, 0, stream>>>(
        X, Wq, Wk, Wv, bq, bk, bv, Xt, Wt, bbp);

    dim3 g1(Mc / 128, Ntot / 128);   // 128 x 18
    qkv_mfma<<<g1, 256, 0, stream>>>(Xt, Wt, bbp, Qb, Kt, Vt);

    attn_mfma<<<dim3(1536), 256, 0, stream>>>(Qb, Kt, Vt, out);
}

// Round 10
// 209.065 us; speedup vs baseline: 1.0030x; 1.0030x over previous
//
#include <hip/hip_runtime.h>
#include <hip/hip_bf16.h>
#include <cmath>

// Problem constants
#define Bc   32
#define Sc_  512
#define Hc   768
#define NHc  12
#define DHc  64
#define Mc   (Bc * Sc_)     // 16384 tokens
#define Ntot (3 * Hc)       // 2304 fused output cols (Q|K|V)

// 0.125 (1/sqrt(DH)) * log2(e): folded into Q so softmax is exp2(s)
#define QSCALE 0.18033688011112042f

// Epilogue stage strides (padded to break 8/16-way bank conflicts)
#define RSTR 132            // row-stage [sm][n] stride (64 rows x 132)
#define VSTR 70             // V-stage  [n][sm] stride (128 rows x 70)

typedef __attribute__((ext_vector_type(8))) short short8v;   // 8 bf16 (4 VGPRs)
typedef __attribute__((ext_vector_type(8))) unsigned short ushort8v;
typedef __attribute__((ext_vector_type(4))) float f32x4;     // MFMA acc

static __device__ __forceinline__ ushort f2b(float f) {
    __hip_bfloat16 h = __float2bfloat16(f);
    return *reinterpret_cast<ushort*>(&h);
}
static __device__ __forceinline__ ushort2 f2b2(float a, float b) {
    __hip_bfloat162 h = __float22bfloat162_rn(float2{a, b});
    return *reinterpret_cast<ushort2*>(&h);
}

// async global->LDS, 16B per lane. HW writes lane i to (wave-uniform lds)+i*16B.
static __device__ __forceinline__ void gl2lds(const ushort* g, ushort* l) {
    __builtin_amdgcn_global_load_lds(
        (const __attribute__((address_space(1))) unsigned int*)g,
        (__attribute__((address_space(3))) unsigned int*)l, 16, 0, 0);
}

// tanh(x) = 1 - 2/(exp2(2x*log2e)+1); exact at +/-inf via rcp(inf)=0
static __device__ __forceinline__ float fast_tanh(float x) {
    float e = __builtin_amdgcn_exp2f(x * 2.885390081777927f);
    return 1.0f - 2.0f * __builtin_amdgcn_rcpf(e + 1.0f);
}

// ---------------------------------------------------------------------------
// Kernel 0 (R0 exact): fp32 -> bf16 tiled repack, coalesced both sides.
//   Xt [m/128][k/8][m%128][8], Wt [n/128][k/8][n%128][8].
// ---------------------------------------------------------------------------
__global__ __launch_bounds__(256) void convert_pack(
    const float* __restrict__ X,
    const float* __restrict__ Wq, const float* __restrict__ Wk,
    const float* __restrict__ Wv,
    const float* __restrict__ bq, const float* __restrict__ bk,
    const float* __restrict__ bv,
    ushort* __restrict__ Xt, ushort* __restrict__ Wt, float* __restrict__ bbp)
{
    const int bx = blockIdx.x;
    const int panel = bx / 12, kcg = bx % 12;   // kcg = 64-k group
    const int t = threadIdx.x;

    __shared__ ushort T[128][68];

    const float* base;
    ushort* out;
    if (panel < 128) {
        base = X + (size_t)panel * 128 * Hc;
        out  = Xt + (size_t)panel * (96 * 1024);
    } else {
        int nblk = panel - 128;                 // 0..17
        int n0 = nblk * 128;
        int z = n0 / Hc;
        int nn0 = n0 - z * Hc;
        const float* W = (z == 0) ? Wq : (z == 1) ? Wk : Wv;
        base = W + (size_t)nn0 * Hc;
        out  = Wt + (size_t)nblk * (96 * 1024);
    }
    const int k0 = kcg * 64;

    const int slot = t & 15, rsub = t >> 4;
    #pragma unroll
    for (int rnd = 0; rnd < 8; ++rnd) {
        int row = rnd * 16 + rsub;
        const float* p = base + (size_t)row * Hc + k0 + slot * 4;
        float4 f = *(const float4*)p;
        ushort2 h0 = f2b2(f.x, f.y);
        ushort2 h1 = f2b2(f.z, f.w);
        ushort4 u;
        u.x = h0.x; u.y = h0.y; u.z = h1.x; u.w = h1.y;
        *(ushort4*)&T[row][slot * 4] = u;
    }
    __syncthreads();

    const int row_w = t & 127, kh = t >> 7;
    #pragma unroll
    for (int rnd = 0; rnd < 4; ++rnd) {
        int kc_l = rnd * 2 + kh;
        ushort4 lo = *(const ushort4*)&T[row_w][kc_l * 8];
        ushort4 hi = *(const ushort4*)&T[row_w][kc_l * 8 + 4];
        ushort8v o;
        o[0] = lo.x; o[1] = lo.y; o[2] = lo.z; o[3] = lo.w;
        o[4] = hi.x; o[5] = hi.y; o[6] = hi.z; o[7] = hi.w;
        *(ushort8v*)&out[(size_t)(kcg * 8 + kc_l) * 1024 + row_w * 8] = o;
    }

    if (bx == 0) {
        for (int i = t; i < Ntot; i += 256) {
            int z2 = i / Hc, nn = i - z2 * Hc;
            bbp[i] = ((z2 == 0) ? bq : (z2 == 1) ? bk : bv)[nn];
        }
    }
}

// ---------------------------------------------------------------------------
// Kernel 1: fused QKV projection, 128x128 tile, BK=32, low-VGPR K-loop (R7),
// LDS-staged wide-store epilogue (R9). NEW vs R9: stage strides padded
// (128->132 row-stage, 64->70 V-stage) to break the 8/16-way LDS bank
// conflicts R9's profile exposed (SQ_LDS_BANK_CONFLICT 3.83M). Values and
// store targets bit-identical; only LDS addresses change.
// Epilogue layouts (per head, head stride S*DH = 32768):
//   Qb: [s][d] row-major, pre-scaled by QSCALE
//   Kt: [kb=s/64][dchunk=d/8][s%64][8]
//   Vt: [kb=s/64][keychunk=(s%64)/8][d][8]
// ---------------------------------------------------------------------------
__global__ __launch_bounds__(256, 4) void qkv_mfma(
    const ushort* __restrict__ Xt, const ushort* __restrict__ Wt,
    const float* __restrict__ bbp,
    ushort* __restrict__ Qb, ushort* __restrict__ Kt, ushort* __restrict__ Vt)
{
    const int tid = threadIdx.x;
    const int wave = tid >> 6, lane = tid & 63;
    const int quad = lane >> 4, l16 = lane & 15;
    const int wr = wave >> 1, wc = wave & 1;
    const int m0 = blockIdx.x * 128;
    const int n0 = blockIdx.y * 128;

    // A-half | B-half during K-loop (8192 used); C-stage after (padded).
    __shared__ __align__(16) ushort S[8960];

    f32x4 acc[4][4];
    #pragma unroll
    for (int i = 0; i < 4; ++i)
        #pragma unroll
        for (int j = 0; j < 4; ++j) acc[i][j] = (f32x4)(0.f);

    const ushort* gA = Xt + (size_t)blockIdx.x * (96 * 1024) + wave * 1024 + lane * 8;
    const ushort* gB = Wt + (size_t)blockIdx.y * (96 * 1024) + wave * 1024 + lane * 8;
    ushort* lA = S + wave * 1024;
    ushort* lB = S + 4096 + wave * 1024;

    for (int t = 0; t < 24; ++t) {
        const ushort* ga = gA + t * 4096;
        const ushort* gb = gB + t * 4096;
        gl2lds(ga,       lA);
        gl2lds(ga + 512, lA + 512);
        gl2lds(gb,       lB);
        gl2lds(gb + 512, lB + 512);
        __syncthreads();

        short8v a[4];
        #pragma unroll
        for (int i = 0; i < 4; ++i)
            a[i] = *(const short8v*)&S[quad * 1024 + (wr * 64 + i * 16 + l16) * 8];
        #pragma unroll
        for (int j = 0; j < 4; ++j) {
            short8v b = *(const short8v*)
                &S[4096 + quad * 1024 + (wc * 64 + j * 16 + l16) * 8];
            #pragma unroll
            for (int i = 0; i < 4; ++i)
                acc[i][j] = __builtin_amdgcn_mfma_f32_16x16x32_bf16(
                    a[i], b, acc[i][j], 0, 0, 0);
        }
        __syncthreads();
    }

    // ---- LDS-staged epilogue: two 64-row rounds through S ----
    // C layout per 16x16 tile: col=l16 (n), row=quad*4+r (m).
    // Round hh covers tiles i in {2hh, 2hh+1}; staged row sm = wr*32 +
    // i2*16 + quad*4 + r  <->  m_loc = (sm>>5)*64 + hh*32 + (sm&31).
    const int z = n0 / Hc;
    #pragma unroll
    for (int hh = 0; hh < 2; ++hh) {
        if (z == 2) {
            // transposed stage [n][sm] stride VSTR: ushort4 writes (4 consec m)
            #pragma unroll
            for (int j = 0; j < 4; ++j) {
                const int n = wc * 64 + j * 16 + l16;
                const float bias = bbp[n0 + n];
                #pragma unroll
                for (int i2 = 0; i2 < 2; ++i2) {
                    const int i = hh * 2 + i2;
                    const int smb = wr * 32 + i2 * 16 + quad * 4;
                    ushort4 o4;
                    o4.x = f2b(acc[i][j][0] + bias);
                    o4.y = f2b(acc[i][j][1] + bias);
                    o4.z = f2b(acc[i][j][2] + bias);
                    o4.w = f2b(acc[i][j][3] + bias);
                    *(ushort4*)&S[n * VSTR + smb] = o4;
                }
            }
        } else {
            // row stage [sm][n] stride RSTR: b16 writes
            #pragma unroll
            for (int j = 0; j < 4; ++j) {
                const int n = wc * 64 + j * 16 + l16;
                const float bias = bbp[n0 + n];
                #pragma unroll
                for (int i2 = 0; i2 < 2; ++i2) {
                    const int i = hh * 2 + i2;
                    const int smb = wr * 32 + i2 * 16 + quad * 4;
                    #pragma unroll
                    for (int r = 0; r < 4; ++r) {
                        float v = acc[i][j][r] + bias;
                        if (z == 0) v *= QSCALE;
                        S[(smb + r) * RSTR + n] = f2b(v);
                    }
                }
            }
        }
        __syncthreads();

        // copy out: 4 x 16B per thread along each layout's contiguous axis
        if (z == 2) {
            #pragma unroll
            for (int cc = 0; cc < 4; ++cc) {
                const int n   = wave * 32 + cc * 8 + (lane & 7);
                const int smv = (lane >> 3) * 8;
                const int m_loc = (smv >> 5) * 64 + hh * 32 + (smv & 31);
                const int m_g = m0 + m_loc;
                const int bb2 = m_g >> 9, s0 = m_g & 511;   // s0&7 == 0
                const int nn = n0 + n - 1536;
                const int hd = nn >> 6, d = nn & 63;
                const size_t hb = (size_t)(bb2 * NHc + hd) * (Sc_ * DHc);
                const size_t ga = hb + (s0 >> 6) * 4096 + ((s0 & 63) >> 3) * 512
                                + (size_t)d * 8;
                *(ushort8v*)&Vt[ga] = *(const ushort8v*)&S[n * VSTR + smv];
            }
        } else {
            #pragma unroll
            for (int cc = 0; cc < 4; ++cc) {
                const int chunk = wave * 256 + cc * 64 + lane;
                const int sm = chunk >> 4, nc = chunk & 15;
                const int m_loc = (sm >> 5) * 64 + hh * 32 + (sm & 31);
                const int m_g = m0 + m_loc;
                const int bb2 = m_g >> 9, s0 = m_g & 511;
                const int nn = n0 + nc * 8 - z * Hc;
                const int hd = nn >> 6, d0 = nn & 63;      // 8-aligned
                const size_t hb = (size_t)(bb2 * NHc + hd) * (Sc_ * DHc);
                const ushort8v val = *(const ushort8v*)&S[sm * RSTR + nc * 8];
                if (z == 0) {
                    *(ushort8v*)&Qb[hb + (size_t)s0 * 64 + d0] = val;
                } else {
                    *(ushort8v*)&Kt[hb + (s0 >> 6) * 4096 + (d0 >> 3) * 512
                                    + (s0 & 63) * 8] = val;
                }
            }
        }
        if (hh == 0) __syncthreads();
    }
}

// ---------------------------------------------------------------------------
// Kernel 2 (R8, kept): attention, 128 q per block (wave = 32 q = 2 u-tiles),
// 1536 blocks, K/V register time-share, 4 waves/SIMD.
// ---------------------------------------------------------------------------
__global__ __launch_bounds__(256, 4) void attn_mfma(
    const ushort* __restrict__ Qb, const ushort* __restrict__ Kt,
    const ushort* __restrict__ Vt, float* __restrict__ out)
{
    const int bid = blockIdx.x;
    const int super = bid >> 5, l = bid & 31;
    const int head_lin = super * 8 + (l & 7);     // 0..383
    const int qq = l >> 3;                        // q-quarter 0..3
    const int b = head_lin / NHc, h = head_lin % NHc;

    const int wave = threadIdx.x >> 6;
    const int lane = threadIdx.x & 63;
    const int quad = lane >> 4, l16 = lane & 15;
    const int q0 = qq * 128 + wave * 32;          // wave owns q0..q0+31
    const int sw = l16 & 7;                       // XOR swizzle key

    const size_t head = (size_t)head_lin * (Sc_ * DHc);
    const ushort* __restrict__ Q = Qb + head;
    const ushort* __restrict__ K = Kt + head;
    const ushort* __restrict__ V = Vt + head;

    __shared__ __align__(16) ushort Plds[4][2048];   // wave-private, 2 u-tiles

    short8v aq[2][2];
    #pragma unroll
    for (int u = 0; u < 2; ++u)
        #pragma unroll
        for (int hf = 0; hf < 2; ++hf)
            aq[u][hf] = *(const short8v*)
                &Q[(size_t)(q0 + u * 16 + l16) * DHc + hf * 32 + quad * 8];

    short8v ones;
    #pragma unroll
    for (int i = 0; i < 8; ++i) ones[i] = (short)0x3F80;   // bf16 1.0

    f32x4 o[2][4], rsum[2];
    #pragma unroll
    for (int u = 0; u < 2; ++u) {
        rsum[u] = (f32x4)(0.f);
        #pragma unroll
        for (int t = 0; t < 4; ++t) o[u][t] = (f32x4)(0.f);
    }

    for (int kb = 0; kb < 8; ++kb) {
        const ushort* Kb_ = K + kb * 4096;
        const ushort* Vb_ = V + kb * 4096;

        // ---- QK phase: only kf live ----
        {
            short8v kf[4][2];
            #pragma unroll
            for (int t = 0; t < 4; ++t) {
                kf[t][0] = *(const short8v*)&Kb_[quad * 512 + (t * 16 + l16) * 8];
                kf[t][1] = *(const short8v*)&Kb_[(4 + quad) * 512 + (t * 16 + l16) * 8];
            }

            #pragma unroll
            for (int u = 0; u < 2; ++u) {
                // S^T: D[key=quad*4+r][q=l16]
                f32x4 sa[4];
                #pragma unroll
                for (int t = 0; t < 4; ++t) {
                    f32x4 s = __builtin_amdgcn_mfma_f32_16x16x32_bf16(
                        kf[t][0], aq[u][0], (f32x4)(0.f), 0, 0, 0);
                    sa[t] = __builtin_amdgcn_mfma_f32_16x16x32_bf16(
                        kf[t][1], aq[u][1], s, 0, 0, 0);
                }

                // p = exp2(s~), pack to bf16, stage to LDS (wave-private)
                #pragma unroll
                for (int t = 0; t < 4; ++t) {
                    float p0 = __builtin_amdgcn_exp2f(sa[t][0]);
                    float p1 = __builtin_amdgcn_exp2f(sa[t][1]);
                    float p2 = __builtin_amdgcn_exp2f(sa[t][2]);
                    float p3 = __builtin_amdgcn_exp2f(sa[t][3]);
                    ushort2 lo = f2b2(p0, p1);
                    ushort2 hi = f2b2(p2, p3);
                    ushort4 pk;
                    pk.x = lo.x; pk.y = lo.y; pk.z = hi.x; pk.w = hi.y;
                    int c = t * 2 + (quad >> 1);            // key chunk 0..7
                    int addr = u * 1024 + l16 * 64 + ((c ^ sw) * 8) + (quad & 1) * 4;
                    *(ushort4*)&Plds[wave][addr] = pk;
                }
            }
        }

        // ---- PV phase: only vf live (re-uses kf's registers) ----
        {
            short8v vf[4][2];
            #pragma unroll
            for (int t = 0; t < 4; ++t) {
                vf[t][0] = *(const short8v*)&Vb_[quad * 512 + (t * 16 + l16) * 8];
                vf[t][1] = *(const short8v*)&Vb_[(4 + quad) * 512 + (t * 16 + l16) * 8];
            }

            #pragma unroll
            for (int u = 0; u < 2; ++u) {
                // P A-frags (q = l16, key chunk = hf*4+quad, swizzled)
                short8v pa0 = *(const short8v*)
                    &Plds[wave][u * 1024 + l16 * 64 + ((quad ^ sw) * 8)];
                short8v pa1 = *(const short8v*)
                    &Plds[wave][u * 1024 + l16 * 64 + (((4 + quad) ^ sw) * 8)];

                // row sums via ones-MFMA
                rsum[u] = __builtin_amdgcn_mfma_f32_16x16x32_bf16(
                    pa0, ones, rsum[u], 0, 0, 0);
                rsum[u] = __builtin_amdgcn_mfma_f32_16x16x32_bf16(
                    pa1, ones, rsum[u], 0, 0, 0);

                // PV: O[q=quad*4+r][d=l16]
                #pragma unroll
                for (int t2 = 0; t2 < 4; ++t2) {
                    o[u][t2] = __builtin_amdgcn_mfma_f32_16x16x32_bf16(
                        pa0, vf[t2][0], o[u][t2], 0, 0, 0);
                    o[u][t2] = __builtin_amdgcn_mfma_f32_16x16x32_bf16(
                        pa1, vf[t2][1], o[u][t2], 0, 0, 0);
                }
            }
        }
    }

    // Epilogue: normalize, tanh, store.
    #pragma unroll
    for (int u = 0; u < 2; ++u) {
        #pragma unroll
        for (int r = 0; r < 4; ++r) {
            float inv = __builtin_amdgcn_rcpf(rsum[u][r]);
            int q = q0 + u * 16 + quad * 4 + r;
            size_t base = ((size_t)b * Sc_ + q) * Hc + h * DHc;
            #pragma unroll
            for (int t2 = 0; t2 < 4; ++t2)
                out[base + t2 * 16 + l16] = fast_tanh(o[u][t2][r] * inv);
        }
    }
}

extern "C" void kernel_launch(void* const* d_in, const int* in_sizes, int n_in,
                              void* d_out, int out_size, void* d_ws, size_t ws_size,
                              hipStream_t stream) {
    const float* X  = (const float*)d_in[0];
    const float* Wq = (const float*)d_in[1];
    const float* bq = (const float*)d_in[2];
    const float* Wk = (const float*)d_in[3];
    const float* bk = (const float*)d_in[4];
    const float* Wv = (const float*)d_in[5];
    const float* bv = (const float*)d_in[6];
    float* out = (float*)d_out;

    ushort* Qb  = (ushort*)d_ws;
    ushort* Kt  = Qb + (size_t)Mc * Hc;
    ushort* Vt  = Kt + (size_t)Mc * Hc;
    ushort* Xt  = Vt + (size_t)Mc * Hc;
    ushort* Wt  = Xt + (size_t)Mc * Hc;
    float*  bbp = (float*)(Wt + (size_t)Ntot * Hc);

    convert_pack<<<dim3(1752), 256, 0, stream>>>(
        X, Wq, Wk, Wv, bq, bk, bv, Xt, Wt, bbp);

    dim3 g1(Mc / 128, Ntot / 128);   // 128 x 18
    qkv_mfma<<<g1, 256, 0, stream>>>(Xt, Wt, bbp, Qb, Kt, Vt);

    attn_mfma<<<dim3(1536), 256, 0, stream>>>(Qb, Kt, Vt, out);
}